// Round 8
// baseline (346.779 us; speedup 1.0000x reference)
//
#include <hip/hip_runtime.h>

#define TT 2048
#define DD 384

typedef float f32x4 __attribute__((ext_vector_type(4)));
typedef float f32x16 __attribute__((ext_vector_type(16)));
typedef short s16x8 __attribute__((ext_vector_type(8)));
typedef unsigned int u32x4 __attribute__((ext_vector_type(4)));

static __device__ __forceinline__ unsigned short f2bf(float f) {
    unsigned int u = __builtin_bit_cast(unsigned int, f);
    u = (u + 0x7fffu + ((u >> 16) & 1u)) >> 16;
    return (unsigned short)u;
}
static __device__ __forceinline__ unsigned int pk2(float a, float b) {
    unsigned int ua = __builtin_bit_cast(unsigned int, a);
    unsigned int ub = __builtin_bit_cast(unsigned int, b);
    ua = (ua + 0x7fffu + ((ua >> 16) & 1u)) >> 16;
    ub = (ub + 0x7fffu + ((ub >> 16) & 1u)) & 0xffff0000u;
    return ua | ub;
}

// LPT balance tables (proven by R7 pass): each j in [0,16) appears exactly 3x, triple sums 22/23
// -> per-CU Sum(j+1) = 25/26 under round-robin {c, c+256, c+512}. eq = 2*EQA + (vrow>>4) bijective.
__device__ __constant__ unsigned char Tj[16][3] = {
    {15,7,0},{15,6,2},{15,4,3},{14,8,0},{14,5,4},{14,6,3},{13,9,0},{13,8,1},
    {13,7,3},{12,9,1},{12,10,1},{12,6,4},{11,9,2},{11,10,2},{11,7,5},{10,8,5}};
__device__ __constant__ unsigned char EQA[16][3] = {
    {0,0,0},{1,0,0},{2,0,0},{0,0,1},{1,0,1},{2,1,1},{0,0,2},{1,1,0},
    {2,1,2},{0,1,1},{1,0,2},{2,2,2},{0,2,1},{1,1,2},{2,2,1},{2,2,2}};

// ---------------- fused QKV projection GEMM, 128x128 tiles, inline fp32->bf16 ----------------
__global__ __launch_bounds__(256, 2) void qkv_gemm(
    const float* __restrict__ x, const float* __restrict__ Wq,
    const float* __restrict__ Wk, const float* __restrict__ Wv,
    unsigned short* __restrict__ qo, unsigned short* __restrict__ ko,
    unsigned short* __restrict__ vto)
{
    __shared__ __align__(16) unsigned short lds[16384];
    const int tid = threadIdx.x;
    const int l   = tid & 63;
    const int w   = tid >> 6;
    const int si  = l & 15;
    const int qq  = l >> 4;
    const int m0  = blockIdx.x * 128;
    const int nb  = blockIdx.y;
    const int wr  = w >> 1, wc = w & 1;

    const int bn = tid & 127;
    const int bk = (tid >> 7) * 16;
    const float* wsrc; int ldw;
    if (nb == 0) { wsrc = (bn < 64) ? (Wq + bn) : (Wk + (bn - 64)); ldw = 64; }
    else         { wsrc = Wv + (nb - 1) * 128 + bn;                 ldw = 384; }

    f32x4 acc[4][4];
    #pragma unroll
    for (int rt = 0; rt < 4; ++rt)
        #pragma unroll
        for (int ct = 0; ct < 4; ++ct) acc[rt][ct] = (f32x4){0.f, 0.f, 0.f, 0.f};

    for (int kt = 0; kt < 12; ++kt) {
        const int k0 = kt * 32;
        #pragma unroll
        for (int i = 0; i < 2; ++i) {
            const int u = tid + 256 * i, r = u >> 2, c = u & 3;
            const float* xp = x + (size_t)(m0 + r) * DD + k0 + c * 8;
            f32x4 x0 = *(const f32x4*)xp;
            f32x4 x1 = *(const f32x4*)(xp + 4);
            s16x8 av;
            av[0] = (short)f2bf(x0[0]); av[1] = (short)f2bf(x0[1]);
            av[2] = (short)f2bf(x0[2]); av[3] = (short)f2bf(x0[3]);
            av[4] = (short)f2bf(x1[0]); av[5] = (short)f2bf(x1[1]);
            av[6] = (short)f2bf(x1[2]); av[7] = (short)f2bf(x1[3]);
            *(s16x8*)&lds[r * 32 + ((c ^ (r & 3)) * 8)] = av;
        }
        {
            float t[16];
            #pragma unroll
            for (int j = 0; j < 16; ++j) t[j] = wsrc[(size_t)(k0 + bk + j) * ldw];
            #pragma unroll
            for (int jj = 0; jj < 2; ++jj) {
                s16x8 bv;
                #pragma unroll
                for (int j = 0; j < 8; ++j) bv[j] = (short)f2bf(t[jj * 8 + j]);
                const int ch = (tid >> 7) * 2 + jj;
                *(s16x8*)&lds[4096 + bn * 32 + ((ch ^ (bn & 3)) * 8)] = bv;
            }
        }
        __syncthreads();

        s16x8 af[4], bf[4];
        #pragma unroll
        for (int rt = 0; rt < 4; ++rt) {
            const int row = wr * 64 + rt * 16 + si;
            af[rt] = *(const s16x8*)&lds[row * 32 + ((qq ^ (row & 3)) * 8)];
        }
        #pragma unroll
        for (int ct = 0; ct < 4; ++ct) {
            const int col = wc * 64 + ct * 16 + si;
            bf[ct] = *(const s16x8*)&lds[4096 + col * 32 + ((qq ^ (col & 3)) * 8)];
        }
        #pragma unroll
        for (int rt = 0; rt < 4; ++rt)
            #pragma unroll
            for (int ct = 0; ct < 4; ++ct)
                acc[rt][ct] = __builtin_amdgcn_mfma_f32_16x16x32_bf16(af[rt], bf[ct], acc[rt][ct], 0, 0, 0);
        __syncthreads();
    }

    if (nb == 0) {
        unsigned short* dst = (wc == 0) ? qo : ko;
        const float sc = (wc == 0) ? 0.125f : 1.0f;
        #pragma unroll
        for (int rt = 0; rt < 4; ++rt)
            #pragma unroll
            for (int ct = 0; ct < 4; ++ct)
                #pragma unroll
                for (int r = 0; r < 4; ++r) {
                    const int m = m0 + wr * 64 + rt * 16 + qq * 4 + r;
                    dst[(size_t)m * 64 + ct * 16 + si] = f2bf(acc[rt][ct][r] * sc);
                }
    } else {
        #pragma unroll
        for (int rt = 0; rt < 4; ++rt)
            #pragma unroll
            for (int ct = 0; ct < 4; ++ct)
                #pragma unroll
                for (int r = 0; r < 4; ++r) {
                    const int m = wr * 64 + rt * 16 + qq * 4 + r;
                    const int n = wc * 64 + ct * 16 + si;
                    lds[n * 128 + (((m >> 3) ^ (n & 7)) * 8) + (m & 7)] = f2bf(acc[rt][ct][r]);
                }
        __syncthreads();
        const int bbat = m0 >> 11, t0 = m0 & 2047;
        #pragma unroll
        for (int i = 0; i < 8; ++i) {
            const int u = tid + 256 * i, n = u >> 4, mc = u & 15;
            s16x8 v = *(const s16x8*)&lds[n * 128 + ((mc ^ (n & 7)) * 8)];
            *(s16x8*)&vto[((size_t)bbat * DD + ((nb - 1) * 128 + n)) * TT + t0 + mc * 8] = v;
        }
    }
}

// ---------------- flash attention, causal, 512-thr, Mq=128, e=64 slices, 3 wgs/CU ----------------
// Register-lean R7: Q staged once into LDS, fragments read JIT per MFMA (same swizzle as K).
// Persistent regs = o0,o1 (32) only; peak live ~76 <= 85 cap of launch_bounds(512,6) -> no spill.
__global__ __launch_bounds__(512, 6) void attn(
    const unsigned short* __restrict__ qg, const unsigned short* __restrict__ kg,
    const unsigned short* __restrict__ vg, float* __restrict__ out)
{
    // shorts: Q [0,8192) [128q][64k] | K[2][64][64] [8192,16384) | V[2][64e][64s] [16384,24576)
    __shared__ __align__(16) unsigned short lds[24576];
    __shared__ float stL[256];

    const int tid = threadIdx.x;
    const int l   = tid & 63;
    const int w   = tid >> 6;    // 0..7
    const int par = w >> 2;      // s-block parity
    const int qb  = w & 3;       // q-band (32 rows)
    const int lo  = l & 31;
    const int hi  = l >> 5;

    const int g  = blockIdx.x;
    const int bb = g & 7;
    const int u  = g >> 3;        // 0..95
    const int vr = u & 31, tp = u >> 5;
    const int j  = Tj[vr & 15][tp];
    const int eq = 2 * EQA[vr & 15][tp] + (vr >> 4);
    const int q0 = j * 128;
    const int e0 = eq * 64;
    const int qrow = q0 + qb * 32 + lo;

    unsigned short* QL = lds;
    unsigned short* Ks = lds + 8192 + par * 4096;
    unsigned short* Vs = lds + 16384 + par * 4096;

    // stage Q once: [128 rows][8 chunks of 8], swizzled like K
    #pragma unroll
    for (int i = 0; i < 2; ++i) {
        const int u2 = tid + 512 * i, r = u2 >> 3, c = u2 & 7;
        s16x8 v = *(const s16x8*)(qg + ((size_t)bb * TT + q0 + r) * 64 + c * 8);
        *(s16x8*)&QL[r * 64 + ((c ^ (r & 7)) * 8)] = v;
    }

    f32x16 o0, o1;
    #pragma unroll
    for (int r = 0; r < 16; ++r) { o0[r] = 0.f; o1[r] = 0.f; }
    float lp = 0.f;

    for (int it = 0; it <= j; ++it) {
        // stage K blocks 2it, 2it+1: [64 s][64 k] swizzled (2 chunks/thread)
        {
            const int p = tid >> 8, r = (tid >> 2) & 63, c = (tid & 3) << 1;
            const unsigned short* kp = kg + ((size_t)bb * TT + (2 * it + p) * 64 + r) * 64;
            s16x8 v0 = *(const s16x8*)(kp + c * 8);
            s16x8 v1 = *(const s16x8*)(kp + (c + 1) * 8);
            *(s16x8*)&lds[8192 + p * 4096 + r * 64 + ((c ^ (r & 7)) * 8)] = v0;
            *(s16x8*)&lds[8192 + p * 4096 + r * 64 + (((c + 1) ^ (r & 7)) * 8)] = v1;
        }
        // stage V^T blocks: [64 e][64 s] swizzled (2 chunks/thread)
        {
            const int p = tid >> 8, r = (tid >> 2) & 63, c = (tid & 3) << 1;
            const unsigned short* vp = vg + ((size_t)bb * DD + e0 + r) * TT + (2 * it + p) * 64;
            s16x8 v0 = *(const s16x8*)(vp + c * 8);
            s16x8 v1 = *(const s16x8*)(vp + (c + 1) * 8);
            *(s16x8*)&lds[16384 + p * 4096 + r * 64 + ((c ^ (r & 7)) * 8)] = v0;
            *(s16x8*)&lds[16384 + p * 4096 + r * 64 + (((c + 1) ^ (r & 7)) * 8)] = v1;
        }
        __syncthreads();

        const int s0 = (2 * it + par) * 64;
        if (s0 <= q0 + qb * 32 + 31) {
            const bool mb = (s0 + 63 > q0 + qb * 32);
            #pragma unroll
            for (int ct = 0; ct < 2; ++ct) {
                f32x16 sa;
                #pragma unroll
                for (int r = 0; r < 16; ++r) sa[r] = 0.f;
                #pragma unroll
                for (int st = 0; st < 4; ++st) {
                    s16x8 kf = *(const s16x8*)&Ks[(ct * 32 + lo) * 64 + (((st * 2 + hi) ^ (lo & 7)) * 8)];
                    const int qr = qb * 32 + lo;
                    s16x8 qv = *(const s16x8*)&QL[qr * 64 + (((st * 2 + hi) ^ (qr & 7)) * 8)];
                    sa = __builtin_amdgcn_mfma_f32_32x32x16_bf16(kf, qv, sa, 0, 0, 0);
                }
                #pragma unroll
                for (int r = 0; r < 16; ++r) {
                    float e = __expf(sa[r]);
                    if (mb) {
                        const int srow = s0 + ct * 32 + (r & 3) + 8 * (r >> 2) + 4 * hi;
                        if (srow > qrow) e = 0.f;
                    }
                    sa[r] = e;
                    lp += e;
                }
                unsigned int d0 = pk2(sa[0], sa[1]),   d1 = pk2(sa[2], sa[3]);
                unsigned int d2 = pk2(sa[4], sa[5]),   d3 = pk2(sa[6], sa[7]);
                unsigned int d4 = pk2(sa[8], sa[9]),   d5 = pk2(sa[10], sa[11]);
                unsigned int d6 = pk2(sa[12], sa[13]), d7 = pk2(sa[14], sa[15]);
                unsigned int sA0 = hi ? d0 : d2, sA1 = hi ? d1 : d3;
                unsigned int rA0 = (unsigned int)__shfl_xor((int)sA0, 32);
                unsigned int rA1 = (unsigned int)__shfl_xor((int)sA1, 32);
                u32x4 fa0 = hi ? (u32x4){rA0, rA1, d2, d3} : (u32x4){d0, d1, rA0, rA1};
                unsigned int sB0 = hi ? d4 : d6, sB1 = hi ? d5 : d7;
                unsigned int rB0 = (unsigned int)__shfl_xor((int)sB0, 32);
                unsigned int rB1 = (unsigned int)__shfl_xor((int)sB1, 32);
                u32x4 fa1 = hi ? (u32x4){rB0, rB1, d6, d7} : (u32x4){d4, d5, rB0, rB1};
                s16x8 a0 = __builtin_bit_cast(s16x8, fa0);
                s16x8 a1 = __builtin_bit_cast(s16x8, fa1);
                {
                    const int el = lo;
                    s16x8 v0 = *(const s16x8*)&Vs[el * 64 + (((ct * 4 + hi) ^ (el & 7)) * 8)];
                    o0 = __builtin_amdgcn_mfma_f32_32x32x16_bf16(a0, v0, o0, 0, 0, 0);
                    s16x8 v1 = *(const s16x8*)&Vs[el * 64 + (((ct * 4 + 2 + hi) ^ (el & 7)) * 8)];
                    o0 = __builtin_amdgcn_mfma_f32_32x32x16_bf16(a1, v1, o0, 0, 0, 0);
                }
                {
                    const int el = 32 + lo;
                    s16x8 v0 = *(const s16x8*)&Vs[el * 64 + (((ct * 4 + hi) ^ (el & 7)) * 8)];
                    o1 = __builtin_amdgcn_mfma_f32_32x32x16_bf16(a0, v0, o1, 0, 0, 0);
                    s16x8 v1 = *(const s16x8*)&Vs[el * 64 + (((ct * 4 + 2 + hi) ^ (el & 7)) * 8)];
                    o1 = __builtin_amdgcn_mfma_f32_32x32x16_bf16(a1, v1, o1, 0, 0, 0);
                }
            }
        }
        __syncthreads();
    }

    lp += __shfl_xor(lp, 32);
    if (hi == 0) stL[par * 128 + qb * 32 + lo] = lp;

    float* fb = (float*)lds;   // [4 qb][32 q][64 e] fp32 = 32KB (reuses Q/K/V region)
    if (par == 1) {
        #pragma unroll
        for (int r = 0; r < 16; ++r) {
            const int rloc = (r & 3) + 8 * (r >> 2) + 4 * hi;
            fb[qb * 2048 + rloc * 64 + lo]      = o0[r];
            fb[qb * 2048 + rloc * 64 + 32 + lo] = o1[r];
        }
    }
    __syncthreads();
    if (par == 0) {
        #pragma unroll
        for (int r = 0; r < 16; ++r) {
            const int rloc = (r & 3) + 8 * (r >> 2) + 4 * hi;
            const float linv = 1.f / (stL[qb * 32 + rloc] + stL[128 + qb * 32 + rloc]);
            float* op = out + ((size_t)bb * TT + q0 + qb * 32 + rloc) * DD + e0;
            op[lo]      = (o0[r] + fb[qb * 2048 + rloc * 64 + lo]) * linv;
            op[32 + lo] = (o1[r] + fb[qb * 2048 + rloc * 64 + 32 + lo]) * linv;
        }
    }
}

extern "C" void kernel_launch(void* const* d_in, const int* in_sizes, int n_in,
                              void* d_out, int out_size, void* d_ws, size_t ws_size,
                              hipStream_t stream)
{
    const float* x  = (const float*)d_in[0];
    const float* Wq = (const float*)d_in[1];
    const float* Wk = (const float*)d_in[2];
    const float* Wv = (const float*)d_in[3];

    unsigned short* qws  = (unsigned short*)d_ws;
    unsigned short* kws  = (unsigned short*)((char*)d_ws + ((size_t)2 << 20));
    unsigned short* vtws = (unsigned short*)((char*)d_ws + ((size_t)4 << 20));

    qkv_gemm<<<dim3(128, 4), dim3(256), 0, stream>>>(x, Wq, Wk, Wv, qws, kws, vtws);
    attn<<<dim3(768), dim3(512), 0, stream>>>(qws, kws, vtws, (float*)d_out);
}

// Round 9
// 178.555 us; speedup vs baseline: 1.9421x; 1.9421x over previous
//
#include <hip/hip_runtime.h>

#define TT 2048
#define DD 384

typedef float f32x4 __attribute__((ext_vector_type(4)));
typedef float f32x16 __attribute__((ext_vector_type(16)));
typedef short s16x8 __attribute__((ext_vector_type(8)));
typedef short s16x2 __attribute__((ext_vector_type(2)));
typedef unsigned int u32x4 __attribute__((ext_vector_type(4)));

static __device__ __forceinline__ unsigned short f2bf(float f) {
    unsigned int u = __builtin_bit_cast(unsigned int, f);
    u = (u + 0x7fffu + ((u >> 16) & 1u)) >> 16;
    return (unsigned short)u;
}
static __device__ __forceinline__ unsigned int pk2(float a, float b) {
#if __has_builtin(__builtin_amdgcn_cvt_pk_bf16_f32)
    s16x2 t = __builtin_amdgcn_cvt_pk_bf16_f32(a, b);
    return __builtin_bit_cast(unsigned int, t);
#else
    unsigned int ua = __builtin_bit_cast(unsigned int, a);
    unsigned int ub = __builtin_bit_cast(unsigned int, b);
    ua = (ua + 0x7fffu + ((ua >> 16) & 1u)) >> 16;
    ub = (ub + 0x7fffu + ((ub >> 16) & 1u)) & 0xffff0000u;
    return ua | ub;
#endif
}

// ---------------- fused QKV projection GEMM, 128x128 tiles, inline fp32->bf16 ----------------
// grid (128 m, 4 nb). nb=0 -> q (scaled 1/8) | k, natural [t][64] bf16; nb=1..3 -> v, transposed vT[e][t].
__global__ __launch_bounds__(256, 2) void qkv_gemm(
    const float* __restrict__ x, const float* __restrict__ Wq,
    const float* __restrict__ Wk, const float* __restrict__ Wv,
    unsigned short* __restrict__ qo, unsigned short* __restrict__ ko,
    unsigned short* __restrict__ vto)
{
    __shared__ __align__(16) unsigned short lds[16384];
    const int tid = threadIdx.x;
    const int l   = tid & 63;
    const int w   = tid >> 6;
    const int si  = l & 15;
    const int qq  = l >> 4;
    const int m0  = blockIdx.x * 128;
    const int nb  = blockIdx.y;
    const int wr  = w >> 1, wc = w & 1;

    const int bn = tid & 127;
    const int bk = (tid >> 7) * 16;
    const float* wsrc; int ldw;
    if (nb == 0) { wsrc = (bn < 64) ? (Wq + bn) : (Wk + (bn - 64)); ldw = 64; }
    else         { wsrc = Wv + (nb - 1) * 128 + bn;                 ldw = 384; }

    f32x4 acc[4][4];
    #pragma unroll
    for (int rt = 0; rt < 4; ++rt)
        #pragma unroll
        for (int ct = 0; ct < 4; ++ct) acc[rt][ct] = (f32x4){0.f, 0.f, 0.f, 0.f};

    for (int kt = 0; kt < 12; ++kt) {
        const int k0 = kt * 32;
        #pragma unroll
        for (int i = 0; i < 2; ++i) {
            const int u = tid + 256 * i, r = u >> 2, c = u & 3;
            const float* xp = x + (size_t)(m0 + r) * DD + k0 + c * 8;
            f32x4 x0 = *(const f32x4*)xp;
            f32x4 x1 = *(const f32x4*)(xp + 4);
            s16x8 av;
            av[0] = (short)f2bf(x0[0]); av[1] = (short)f2bf(x0[1]);
            av[2] = (short)f2bf(x0[2]); av[3] = (short)f2bf(x0[3]);
            av[4] = (short)f2bf(x1[0]); av[5] = (short)f2bf(x1[1]);
            av[6] = (short)f2bf(x1[2]); av[7] = (short)f2bf(x1[3]);
            *(s16x8*)&lds[r * 32 + ((c ^ (r & 3)) * 8)] = av;
        }
        {
            float t[16];
            #pragma unroll
            for (int j = 0; j < 16; ++j) t[j] = wsrc[(size_t)(k0 + bk + j) * ldw];
            #pragma unroll
            for (int jj = 0; jj < 2; ++jj) {
                s16x8 bv;
                #pragma unroll
                for (int j = 0; j < 8; ++j) bv[j] = (short)f2bf(t[jj * 8 + j]);
                const int ch = (tid >> 7) * 2 + jj;
                *(s16x8*)&lds[4096 + bn * 32 + ((ch ^ (bn & 3)) * 8)] = bv;
            }
        }
        __syncthreads();

        s16x8 af[4], bf[4];
        #pragma unroll
        for (int rt = 0; rt < 4; ++rt) {
            const int row = wr * 64 + rt * 16 + si;
            af[rt] = *(const s16x8*)&lds[row * 32 + ((qq ^ (row & 3)) * 8)];
        }
        #pragma unroll
        for (int ct = 0; ct < 4; ++ct) {
            const int col = wc * 64 + ct * 16 + si;
            bf[ct] = *(const s16x8*)&lds[4096 + col * 32 + ((qq ^ (col & 3)) * 8)];
        }
        #pragma unroll
        for (int rt = 0; rt < 4; ++rt)
            #pragma unroll
            for (int ct = 0; ct < 4; ++ct)
                acc[rt][ct] = __builtin_amdgcn_mfma_f32_16x16x32_bf16(af[rt], bf[ct], acc[rt][ct], 0, 0, 0);
        __syncthreads();
    }

    if (nb == 0) {
        unsigned short* dst = (wc == 0) ? qo : ko;
        const float sc = (wc == 0) ? 0.125f : 1.0f;  // fold 1/sqrt(K) into q
        #pragma unroll
        for (int rt = 0; rt < 4; ++rt)
            #pragma unroll
            for (int ct = 0; ct < 4; ++ct)
                #pragma unroll
                for (int r = 0; r < 4; ++r) {
                    const int m = m0 + wr * 64 + rt * 16 + qq * 4 + r;
                    dst[(size_t)m * 64 + ct * 16 + si] = f2bf(acc[rt][ct][r] * sc);
                }
    } else {
        #pragma unroll
        for (int rt = 0; rt < 4; ++rt)
            #pragma unroll
            for (int ct = 0; ct < 4; ++ct)
                #pragma unroll
                for (int r = 0; r < 4; ++r) {
                    const int m = wr * 64 + rt * 16 + qq * 4 + r;
                    const int n = wc * 64 + ct * 16 + si;
                    lds[n * 128 + (((m >> 3) ^ (n & 7)) * 8) + (m & 7)] = f2bf(acc[rt][ct][r]);
                }
        __syncthreads();
        const int bbat = m0 >> 11, t0 = m0 & 2047;
        #pragma unroll
        for (int i = 0; i < 8; ++i) {
            const int u = tid + 256 * i, n = u >> 4, mc = u & 15;
            s16x8 v = *(const s16x8*)&lds[n * 128 + ((mc ^ (n & 7)) * 8)];
            *(s16x8*)&vto[((size_t)bbat * DD + ((nb - 1) * 128 + n)) * TT + t0 + mc * 8] = v;
        }
    }
}

// ---------------- flash attention, causal, 512-thr wgs, s-parity split, SW-pipelined staging ----------------
// R5 structure (best measured: 56us, no spill) + register prefetch of next iteration's K/V:
//   commit regs->LDS ; barrier ; issue loads(it+1) ; compute(it) ; barrier   -- global latency hidden by compute.
// grid 512: bb=g&7, eq=(g>>3)&3 (96 e-cols), j snake-paired. Waves 0-3: even s-blocks; 4-7: odd.
__global__ __launch_bounds__(512, 4) void attn(
    const unsigned short* __restrict__ qg, const unsigned short* __restrict__ kg,
    const unsigned short* __restrict__ vg, float* __restrict__ out)
{
    __shared__ __align__(16) unsigned short lds[20480]; // K[2][64][64] 16KB | V[2][96][64] 24KB; combine reuses
    __shared__ float stL[256];

    const int tid = threadIdx.x;
    const int l   = tid & 63;
    const int w   = tid >> 6;    // 0..7
    const int par = w >> 2;      // s-parity group
    const int qb  = w & 3;       // q-band (32 rows)
    const int lo  = l & 31;
    const int hi  = l >> 5;

    const int g  = blockIdx.x;
    const int bb = g & 7;
    const int eq = (g >> 3) & 3;
    const int jidx = g >> 5;
    const int j  = (g < 256) ? jidx : (23 - jidx);
    const int q0 = j * 128;
    const int e0 = eq * 96;
    const int qrow = q0 + qb * 32 + lo;

    // Q as B-operand frags (q pre-scaled by 1/8 in qkv)
    s16x8 qf[4];
    {
        const unsigned short* qp = qg + ((size_t)bb * TT + qrow) * 64;
        #pragma unroll
        for (int st = 0; st < 4; ++st) qf[st] = *(const s16x8*)(qp + st * 16 + hi * 8);
    }

    f32x16 o[3];
    #pragma unroll
    for (int et = 0; et < 3; ++et)
        #pragma unroll
        for (int r = 0; r < 16; ++r) o[et][r] = 0.f;
    float lp = 0.f;

    unsigned short* Ks = lds + par * 4096;
    unsigned short* Vs = lds + 8192 + par * 6144;

    // ---- staging geometry (per-thread constants) ----
    const int kr = (tid >> 3) & 63, kc = tid & 7;
    const unsigned short* ksrc0 = kg + ((size_t)bb * TT + kr) * 64 + kc * 8;          // p=0, it=0
    const unsigned short* ksrc1 = ksrc0 + 64 * 64;                                     // p=1
    const int kd0 = kr * 64 + ((kc ^ (kr & 7)) * 8);
    const int kd1 = 4096 + kd0;
    int vrr[3], vdd[3];
    const unsigned short* vsrc[3];
    #pragma unroll
    for (int i = 0; i < 3; ++i) {
        const int u2 = tid + 512 * i;
        const int p = (u2 >= 768) ? 1 : 0;
        const int idx = u2 - 768 * p;
        const int r = idx >> 3, c = idx & 7;
        vsrc[i] = vg + ((size_t)bb * DD + e0 + r) * TT + p * 64 + c * 8;              // it=0
        vdd[i]  = 8192 + p * 6144 + r * 64 + ((c ^ (r & 7)) * 8);
        vrr[i]  = r;
    }

    // ---- prefetch iteration 0 ----
    s16x8 kpre0 = *(const s16x8*)ksrc0;
    s16x8 kpre1 = *(const s16x8*)ksrc1;
    s16x8 vpre[3];
    #pragma unroll
    for (int i = 0; i < 3; ++i) vpre[i] = *(const s16x8*)vsrc[i];

    for (int it = 0; it <= j; ++it) {
        // commit prefetched tiles to LDS (compiler inserts vmcnt wait here)
        *(s16x8*)&lds[kd0] = kpre0;
        *(s16x8*)&lds[kd1] = kpre1;
        #pragma unroll
        for (int i = 0; i < 3; ++i) *(s16x8*)&lds[vdd[i]] = vpre[i];
        __syncthreads();

        // fire next iteration's loads; they fly during compute
        if (it < j) {
            const size_t kof = (size_t)(it + 1) * 8192;   // 2 blocks * 64 rows * 64
            kpre0 = *(const s16x8*)(ksrc0 + kof);
            kpre1 = *(const s16x8*)(ksrc1 + kof);
            const int vof = (it + 1) * 128;
            #pragma unroll
            for (int i = 0; i < 3; ++i) vpre[i] = *(const s16x8*)(vsrc[i] + vof);
        }

        const int s0 = (2 * it + par) * 64;
        if (s0 <= q0 + qb * 32 + 31) {
            const bool mb = (s0 + 63 > q0 + qb * 32);
            #pragma unroll
            for (int ct = 0; ct < 2; ++ct) {
                f32x16 sa;
                #pragma unroll
                for (int r = 0; r < 16; ++r) sa[r] = 0.f;
                #pragma unroll
                for (int st = 0; st < 4; ++st) {
                    s16x8 kf = *(const s16x8*)&Ks[(ct * 32 + lo) * 64 + (((st * 2 + hi) ^ (lo & 7)) * 8)];
                    sa = __builtin_amdgcn_mfma_f32_32x32x16_bf16(kf, qf[st], sa, 0, 0, 0);
                }
                float pv[16];
                #pragma unroll
                for (int r = 0; r < 16; ++r) {
                    float e = __expf(sa[r]);
                    if (mb) {
                        const int srow = s0 + ct * 32 + (r & 3) + 8 * (r >> 2) + 4 * hi;
                        if (srow > qrow) e = 0.f;
                    }
                    pv[r] = e;
                    lp += e;
                }
                unsigned int d0 = pk2(pv[0], pv[1]),   d1 = pk2(pv[2], pv[3]);
                unsigned int d2 = pk2(pv[4], pv[5]),   d3 = pk2(pv[6], pv[7]);
                unsigned int d4 = pk2(pv[8], pv[9]),   d5 = pk2(pv[10], pv[11]);
                unsigned int d6 = pk2(pv[12], pv[13]), d7 = pk2(pv[14], pv[15]);
                unsigned int sA0 = hi ? d0 : d2, sA1 = hi ? d1 : d3;
                unsigned int rA0 = (unsigned int)__shfl_xor((int)sA0, 32);
                unsigned int rA1 = (unsigned int)__shfl_xor((int)sA1, 32);
                u32x4 fa0 = hi ? (u32x4){rA0, rA1, d2, d3} : (u32x4){d0, d1, rA0, rA1};
                unsigned int sB0 = hi ? d4 : d6, sB1 = hi ? d5 : d7;
                unsigned int rB0 = (unsigned int)__shfl_xor((int)sB0, 32);
                unsigned int rB1 = (unsigned int)__shfl_xor((int)sB1, 32);
                u32x4 fa1 = hi ? (u32x4){rB0, rB1, d6, d7} : (u32x4){d4, d5, rB0, rB1};
                s16x8 a0 = __builtin_bit_cast(s16x8, fa0);
                s16x8 a1 = __builtin_bit_cast(s16x8, fa1);
                #pragma unroll
                for (int et = 0; et < 3; ++et) {
                    const int el = et * 32 + lo;
                    s16x8 v0 = *(const s16x8*)&Vs[el * 64 + (((ct * 4 + hi) ^ (el & 7)) * 8)];
                    o[et] = __builtin_amdgcn_mfma_f32_32x32x16_bf16(a0, v0, o[et], 0, 0, 0);
                    s16x8 v1 = *(const s16x8*)&Vs[el * 64 + (((ct * 4 + 2 + hi) ^ (el & 7)) * 8)];
                    o[et] = __builtin_amdgcn_mfma_f32_32x32x16_bf16(a1, v1, o[et], 0, 0, 0);
                }
            }
        }
        __syncthreads();
    }

    // l totals per parity -> stL
    lp += __shfl_xor(lp, 32);
    if (hi == 0) stL[par * 128 + qb * 32 + lo] = lp;
    __syncthreads();

    // combine parity partials via LDS (2 phases of 2 q-bands; 24KB each), normalize, store
    float* fb = (float*)lds;
    #pragma unroll
    for (int ph = 0; ph < 2; ++ph) {
        if (par == 1 && (qb >> 1) == ph) {
            const int slot = qb & 1;
            #pragma unroll
            for (int r = 0; r < 16; ++r) {
                const int rloc = (r & 3) + 8 * (r >> 2) + 4 * hi;
                #pragma unroll
                for (int et = 0; et < 3; ++et)
                    fb[slot * 3072 + rloc * 96 + et * 32 + lo] = o[et][r];
            }
        }
        __syncthreads();
        if (par == 0 && (qb >> 1) == ph) {
            const int slot = qb & 1;
            #pragma unroll
            for (int r = 0; r < 16; ++r) {
                const int rloc = (r & 3) + 8 * (r >> 2) + 4 * hi;
                const float linv = 1.f / (stL[qb * 32 + rloc] + stL[128 + qb * 32 + rloc]);
                float* op = out + ((size_t)bb * TT + q0 + qb * 32 + rloc) * DD + e0;
                #pragma unroll
                for (int et = 0; et < 3; ++et)
                    op[et * 32 + lo] = (o[et][r] + fb[slot * 3072 + rloc * 96 + et * 32 + lo]) * linv;
            }
        }
        __syncthreads();
    }
}

extern "C" void kernel_launch(void* const* d_in, const int* in_sizes, int n_in,
                              void* d_out, int out_size, void* d_ws, size_t ws_size,
                              hipStream_t stream)
{
    const float* x  = (const float*)d_in[0];
    const float* Wq = (const float*)d_in[1];
    const float* Wk = (const float*)d_in[2];
    const float* Wv = (const float*)d_in[3];

    // ws: q [0,2M) | k [2M,4M) | vT [4M,16M)
    unsigned short* qws  = (unsigned short*)d_ws;
    unsigned short* kws  = (unsigned short*)((char*)d_ws + ((size_t)2 << 20));
    unsigned short* vtws = (unsigned short*)((char*)d_ws + ((size_t)4 << 20));

    qkv_gemm<<<dim3(128, 4), dim3(256), 0, stream>>>(x, Wq, Wk, Wv, qws, kws, vtws);
    attn<<<dim3(512), dim3(512), 0, stream>>>(qws, kws, vtws, (float*)d_out);
}

// Round 10
// 143.391 us; speedup vs baseline: 2.4184x; 1.2452x over previous
//
#include <hip/hip_runtime.h>

#define TT 2048
#define DD 384

typedef float f32x4 __attribute__((ext_vector_type(4)));
typedef float f32x16 __attribute__((ext_vector_type(16)));
typedef short s16x8 __attribute__((ext_vector_type(8)));
typedef short s16x2 __attribute__((ext_vector_type(2)));
typedef unsigned int u32x4 __attribute__((ext_vector_type(4)));

typedef __attribute__((address_space(3))) unsigned char* as3p;
typedef const __attribute__((address_space(1))) unsigned char* as1p;
// HW direct global->LDS copy: 16B/lane x 64 lanes = 1KB per call; LDS dest = uniform base + lane*16.
#define GLLDS(gsrc, ldst) __builtin_amdgcn_global_load_lds((as1p)(gsrc), (as3p)(ldst), 16, 0, 0)

static __device__ __forceinline__ unsigned short f2bf(float f) {
    unsigned int u = __builtin_bit_cast(unsigned int, f);
    u = (u + 0x7fffu + ((u >> 16) & 1u)) >> 16;
    return (unsigned short)u;
}
static __device__ __forceinline__ unsigned int pk2(float a, float b) {
#if __has_builtin(__builtin_amdgcn_cvt_pk_bf16_f32)
    s16x2 t = __builtin_amdgcn_cvt_pk_bf16_f32(a, b);
    return __builtin_bit_cast(unsigned int, t);
#else
    unsigned int ua = __builtin_bit_cast(unsigned int, a);
    unsigned int ub = __builtin_bit_cast(unsigned int, b);
    ua = (ua + 0x7fffu + ((ua >> 16) & 1u)) >> 16;
    ub = (ub + 0x7fffu + ((ub >> 16) & 1u)) & 0xffff0000u;
    return ua | ub;
#endif
}

// ---------------- fused QKV projection GEMM, 128x128 tiles, inline fp32->bf16 ----------------
// nb=0 -> q (scaled 1/8, natural [t][64]) | k (PRE-SWIZZLED: within each row, 8-chunk c stored at c^(t&7));
// nb=1..3 -> v transposed vT[e][t], pre-swizzled within each 64-t block (chunk c at c^(e&7)).
// Pre-swizzle makes the attn kernel's global_load_lds image directly MFMA-read bank-balanced.
__global__ __launch_bounds__(256, 2) void qkv_gemm(
    const float* __restrict__ x, const float* __restrict__ Wq,
    const float* __restrict__ Wk, const float* __restrict__ Wv,
    unsigned short* __restrict__ qo, unsigned short* __restrict__ ko,
    unsigned short* __restrict__ vto)
{
    __shared__ __align__(16) unsigned short lds[16384];
    const int tid = threadIdx.x;
    const int l   = tid & 63;
    const int w   = tid >> 6;
    const int si  = l & 15;
    const int qq  = l >> 4;
    const int m0  = blockIdx.x * 128;
    const int nb  = blockIdx.y;
    const int wr  = w >> 1, wc = w & 1;

    const int bn = tid & 127;
    const int bk = (tid >> 7) * 16;
    const float* wsrc; int ldw;
    if (nb == 0) { wsrc = (bn < 64) ? (Wq + bn) : (Wk + (bn - 64)); ldw = 64; }
    else         { wsrc = Wv + (nb - 1) * 128 + bn;                 ldw = 384; }

    f32x4 acc[4][4];
    #pragma unroll
    for (int rt = 0; rt < 4; ++rt)
        #pragma unroll
        for (int ct = 0; ct < 4; ++ct) acc[rt][ct] = (f32x4){0.f, 0.f, 0.f, 0.f};

    for (int kt = 0; kt < 12; ++kt) {
        const int k0 = kt * 32;
        #pragma unroll
        for (int i = 0; i < 2; ++i) {
            const int u = tid + 256 * i, r = u >> 2, c = u & 3;
            const float* xp = x + (size_t)(m0 + r) * DD + k0 + c * 8;
            f32x4 x0 = *(const f32x4*)xp;
            f32x4 x1 = *(const f32x4*)(xp + 4);
            s16x8 av;
            av[0] = (short)f2bf(x0[0]); av[1] = (short)f2bf(x0[1]);
            av[2] = (short)f2bf(x0[2]); av[3] = (short)f2bf(x0[3]);
            av[4] = (short)f2bf(x1[0]); av[5] = (short)f2bf(x1[1]);
            av[6] = (short)f2bf(x1[2]); av[7] = (short)f2bf(x1[3]);
            *(s16x8*)&lds[r * 32 + ((c ^ (r & 3)) * 8)] = av;
        }
        {
            float t[16];
            #pragma unroll
            for (int j = 0; j < 16; ++j) t[j] = wsrc[(size_t)(k0 + bk + j) * ldw];
            #pragma unroll
            for (int jj = 0; jj < 2; ++jj) {
                s16x8 bv;
                #pragma unroll
                for (int j = 0; j < 8; ++j) bv[j] = (short)f2bf(t[jj * 8 + j]);
                const int ch = (tid >> 7) * 2 + jj;
                *(s16x8*)&lds[4096 + bn * 32 + ((ch ^ (bn & 3)) * 8)] = bv;
            }
        }
        __syncthreads();

        s16x8 af[4], bf[4];
        #pragma unroll
        for (int rt = 0; rt < 4; ++rt) {
            const int row = wr * 64 + rt * 16 + si;
            af[rt] = *(const s16x8*)&lds[row * 32 + ((qq ^ (row & 3)) * 8)];
        }
        #pragma unroll
        for (int ct = 0; ct < 4; ++ct) {
            const int col = wc * 64 + ct * 16 + si;
            bf[ct] = *(const s16x8*)&lds[4096 + col * 32 + ((qq ^ (col & 3)) * 8)];
        }
        #pragma unroll
        for (int rt = 0; rt < 4; ++rt)
            #pragma unroll
            for (int ct = 0; ct < 4; ++ct)
                acc[rt][ct] = __builtin_amdgcn_mfma_f32_16x16x32_bf16(af[rt], bf[ct], acc[rt][ct], 0, 0, 0);
        __syncthreads();
    }

    if (nb == 0) {
        if (wc == 0) {  // q: natural layout, fold 1/sqrt(K)
            #pragma unroll
            for (int rt = 0; rt < 4; ++rt)
                #pragma unroll
                for (int ct = 0; ct < 4; ++ct)
                    #pragma unroll
                    for (int r = 0; r < 4; ++r) {
                        const int m = m0 + wr * 64 + rt * 16 + qq * 4 + r;
                        qo[(size_t)m * 64 + ct * 16 + si] = f2bf(acc[rt][ct][r] * 0.125f);
                    }
        } else {        // k: pre-swizzled (chunk c -> c ^ (t&7))
            #pragma unroll
            for (int rt = 0; rt < 4; ++rt)
                #pragma unroll
                for (int ct = 0; ct < 4; ++ct)
                    #pragma unroll
                    for (int r = 0; r < 4; ++r) {
                        const int m = m0 + wr * 64 + rt * 16 + qq * 4 + r;
                        const int col = ct * 16 + si;
                        ko[(size_t)m * 64 + (((col >> 3) ^ (m & 7)) * 8) + (col & 7)] = f2bf(acc[rt][ct][r]);
                    }
        }
    } else {
        #pragma unroll
        for (int rt = 0; rt < 4; ++rt)
            #pragma unroll
            for (int ct = 0; ct < 4; ++ct)
                #pragma unroll
                for (int r = 0; r < 4; ++r) {
                    const int m = wr * 64 + rt * 16 + qq * 4 + r;
                    const int n = wc * 64 + ct * 16 + si;
                    lds[n * 128 + (((m >> 3) ^ (n & 7)) * 8) + (m & 7)] = f2bf(acc[rt][ct][r]);
                }
        __syncthreads();
        const int bbat = m0 >> 11, t0 = m0 & 2047;
        #pragma unroll
        for (int i = 0; i < 8; ++i) {
            const int u = tid + 256 * i, n = u >> 4, mc = u & 15;
            s16x8 v = *(const s16x8*)&lds[n * 128 + ((mc ^ (n & 7)) * 8)];
            // pre-swizzle within each 64-t block: chunk (mc&7) stored at (mc&7)^(e&7); e&7 == n&7
            *(s16x8*)&vto[((size_t)bbat * DD + ((nb - 1) * 128 + n)) * TT
                          + t0 + (mc >> 3) * 64 + (((mc & 7) ^ (n & 7)) * 8)] = v;
        }
    }
}

// ---------------- flash attention, causal, 512-thr, s-parity split, async dbuf staging ----------------
// R5 structure + global_load_lds double-buffer: ONE barrier/iter; copies for it+1 issued right after
// the barrier and drained by the NEXT barrier's vmcnt(0) (a full compute-phase later). No data regs
// used for staging -> no spill risk. K/V arrive pre-swizzled from qkv_gemm (verbatim LDS image).
// grid 512: bb=g&7, eq=(g>>3)&3 (96 e-cols), j snake-paired (j, 15-j per CU). Waves 0-3 even s, 4-7 odd.
__global__ __launch_bounds__(512, 4) void attn(
    const unsigned short* __restrict__ qg, const unsigned short* __restrict__ kg,
    const unsigned short* __restrict__ vg, float* __restrict__ out)
{
    // bytes: K dbuf [0,32768) = 2 x [128 t][128B] | V dbuf [32768,81920) = 2 x [2 par][96 e][128B]
    // post-loop overlay: fb fp32 [0,24576) + stL fp32 [24576,25600)
    __shared__ __align__(16) unsigned short lds[40960];

    const int tid = threadIdx.x;
    const int l   = tid & 63;
    const int w   = tid >> 6;    // 0..7
    const int par = w >> 2;      // s-parity group
    const int qb  = w & 3;       // q-band (32 rows)
    const int lo  = l & 31;
    const int hi  = l >> 5;

    const int g  = blockIdx.x;
    const int bb = g & 7;
    const int eq = (g >> 3) & 3;
    const int jidx = g >> 5;
    const int j  = (g < 256) ? jidx : (23 - jidx);
    const int q0 = j * 128;
    const int e0 = eq * 96;
    const int qrow = q0 + qb * 32 + lo;

    // Q as B-operand frags (q pre-scaled by 1/8 in qkv; natural layout)
    s16x8 qf[4];
    {
        const unsigned short* qp = qg + ((size_t)bb * TT + qrow) * 64;
        #pragma unroll
        for (int st = 0; st < 4; ++st) qf[st] = *(const s16x8*)(qp + st * 16 + hi * 8);
    }

    f32x16 o[3];
    #pragma unroll
    for (int et = 0; et < 3; ++et)
        #pragma unroll
        for (int r = 0; r < 16; ++r) o[et][r] = 0.f;
    float lp = 0.f;

    // ---- async staging: wave w copies K chunks 2w..2w+1 and V chunks 3w..3w+2 (1KB each) ----
    const unsigned short* kbase = kg + (size_t)bb * TT * 64;
    const unsigned short* vbase = vg + ((size_t)bb * DD + e0) * TT;

    #define STAGE(IT, BUF)                                                                  \
    {                                                                                       \
        const unsigned short* kb = kbase + (size_t)(IT) * 128 * 64;                         \
        unsigned short* kl = &lds[(BUF) * 8192];                                            \
        GLLDS(kb + (2 * w) * 512 + l * 8,     &kl[(2 * w) * 512]);                          \
        GLLDS(kb + (2 * w + 1) * 512 + l * 8, &kl[(2 * w + 1) * 512]);                      \
        unsigned short* vl = &lds[16384 + (BUF) * 12288];                                   \
        _Pragma("unroll")                                                                   \
        for (int c3 = 0; c3 < 3; ++c3) {                                                    \
            const int ch = 3 * w + c3;                                                      \
            const int p = ch / 12, rr = (ch % 12) * 8;                                      \
            const unsigned short* vb = vbase + ((size_t)(rr + (l >> 3))) * TT               \
                                       + (IT) * 128 + p * 64 + (l & 7) * 8;                 \
            GLLDS(vb, &vl[ch * 512]);                                                       \
        }                                                                                   \
    }

    STAGE(0, 0);   // prologue

    for (int it = 0; it <= j; ++it) {
        const int buf = it & 1;
        __syncthreads();   // vmcnt(0)+barrier: copies into buf complete; all waves done with 1-buf

        if (it < j) STAGE(it + 1, 1 - buf);   // fly during compute

        const unsigned short* Ks = &lds[buf * 8192 + par * 4096];
        const unsigned short* Vs = &lds[16384 + buf * 12288 + par * 6144];

        const int s0 = (2 * it + par) * 64;
        if (s0 <= q0 + qb * 32 + 31) {
            const bool mb = (s0 + 63 > q0 + qb * 32);
            #pragma unroll
            for (int ct = 0; ct < 2; ++ct) {
                f32x16 sa;
                #pragma unroll
                for (int r = 0; r < 16; ++r) sa[r] = 0.f;
                #pragma unroll
                for (int st = 0; st < 4; ++st) {
                    s16x8 kf = *(const s16x8*)&Ks[(ct * 32 + lo) * 64 + (((st * 2 + hi) ^ (lo & 7)) * 8)];
                    sa = __builtin_amdgcn_mfma_f32_32x32x16_bf16(kf, qf[st], sa, 0, 0, 0);
                }
                float pv[16];
                #pragma unroll
                for (int r = 0; r < 16; ++r) {
                    float e = __expf(sa[r]);
                    if (mb) {
                        const int srow = s0 + ct * 32 + (r & 3) + 8 * (r >> 2) + 4 * hi;
                        if (srow > qrow) e = 0.f;
                    }
                    pv[r] = e;
                    lp += e;
                }
                unsigned int d0 = pk2(pv[0], pv[1]),   d1 = pk2(pv[2], pv[3]);
                unsigned int d2 = pk2(pv[4], pv[5]),   d3 = pk2(pv[6], pv[7]);
                unsigned int d4 = pk2(pv[8], pv[9]),   d5 = pk2(pv[10], pv[11]);
                unsigned int d6 = pk2(pv[12], pv[13]), d7 = pk2(pv[14], pv[15]);
                unsigned int sA0 = hi ? d0 : d2, sA1 = hi ? d1 : d3;
                unsigned int rA0 = (unsigned int)__shfl_xor((int)sA0, 32);
                unsigned int rA1 = (unsigned int)__shfl_xor((int)sA1, 32);
                u32x4 fa0 = hi ? (u32x4){rA0, rA1, d2, d3} : (u32x4){d0, d1, rA0, rA1};
                unsigned int sB0 = hi ? d4 : d6, sB1 = hi ? d5 : d7;
                unsigned int rB0 = (unsigned int)__shfl_xor((int)sB0, 32);
                unsigned int rB1 = (unsigned int)__shfl_xor((int)sB1, 32);
                u32x4 fa1 = hi ? (u32x4){rB0, rB1, d6, d7} : (u32x4){d4, d5, rB0, rB1};
                s16x8 a0 = __builtin_bit_cast(s16x8, fa0);
                s16x8 a1 = __builtin_bit_cast(s16x8, fa1);
                #pragma unroll
                for (int et = 0; et < 3; ++et) {
                    const int el = et * 32 + lo;
                    s16x8 v0 = *(const s16x8*)&Vs[el * 64 + (((ct * 4 + hi) ^ (el & 7)) * 8)];
                    o[et] = __builtin_amdgcn_mfma_f32_32x32x16_bf16(a0, v0, o[et], 0, 0, 0);
                    s16x8 v1 = *(const s16x8*)&Vs[el * 64 + (((ct * 4 + 2 + hi) ^ (el & 7)) * 8)];
                    o[et] = __builtin_amdgcn_mfma_f32_32x32x16_bf16(a1, v1, o[et], 0, 0, 0);
                }
            }
        }
    }
    __syncthreads();   // loop ends on compute: drain before overlaying buffers

    // l totals per parity -> stL (overlaid at bytes [24576, 25600))
    float* fb  = (float*)lds;
    float* stL = (float*)lds + 6144;
    lp += __shfl_xor(lp, 32);
    if (hi == 0) stL[par * 128 + qb * 32 + lo] = lp;
    __syncthreads();

    // combine parity partials (2 phases of 2 q-bands; 12KB/slot), normalize, store
    #pragma unroll
    for (int ph = 0; ph < 2; ++ph) {
        if (par == 1 && (qb >> 1) == ph) {
            const int slot = qb & 1;
            #pragma unroll
            for (int r = 0; r < 16; ++r) {
                const int rloc = (r & 3) + 8 * (r >> 2) + 4 * hi;
                #pragma unroll
                for (int et = 0; et < 3; ++et)
                    fb[slot * 3072 + rloc * 96 + et * 32 + lo] = o[et][r];
            }
        }
        __syncthreads();
        if (par == 0 && (qb >> 1) == ph) {
            const int slot = qb & 1;
            #pragma unroll
            for (int r = 0; r < 16; ++r) {
                const int rloc = (r & 3) + 8 * (r >> 2) + 4 * hi;
                const float linv = 1.f / (stL[qb * 32 + rloc] + stL[128 + qb * 32 + rloc]);
                float* op = out + ((size_t)bb * TT + q0 + qb * 32 + rloc) * DD + e0;
                #pragma unroll
                for (int et = 0; et < 3; ++et)
                    op[et * 32 + lo] = (o[et][r] + fb[slot * 3072 + rloc * 96 + et * 32 + lo]) * linv;
            }
        }
        __syncthreads();
    }
}

extern "C" void kernel_launch(void* const* d_in, const int* in_sizes, int n_in,
                              void* d_out, int out_size, void* d_ws, size_t ws_size,
                              hipStream_t stream)
{
    const float* x  = (const float*)d_in[0];
    const float* Wq = (const float*)d_in[1];
    const float* Wk = (const float*)d_in[2];
    const float* Wv = (const float*)d_in[3];

    // ws: q [0,2M) | k [2M,4M) | vT [4M,16M)
    unsigned short* qws  = (unsigned short*)d_ws;
    unsigned short* kws  = (unsigned short*)((char*)d_ws + ((size_t)2 << 20));
    unsigned short* vtws = (unsigned short*)((char*)d_ws + ((size_t)4 << 20));

    qkv_gemm<<<dim3(128, 4), dim3(256), 0, stream>>>(x, Wq, Wk, Wv, qws, kws, vtws);
    attn<<<dim3(512), dim3(512), 0, stream>>>(qws, kws, vtws, (float*)d_out);
}